// Round 3
// baseline (195.125 us; speedup 1.0000x reference)
//
#include <hip/hip_runtime.h>

// ---------------------------------------------------------------------------
// CausalSelfAttention, banded (band=256), B=2 T=2048 C=1024 H=16 hd=64.
// cvt(fp32->bf16) -> fused QKV bf16-MFMA GEMM (BK=64 two-slab staging,
// V written TRANSPOSED [b,h,d,t], coalesced LDS-repack epilogue) -> banded
// MFMA flash attention (no barriers) -> output projection GEMM (fp32 out).
// Workspace layout (bytes):
//   [0,8M)    xb   bf16 [4096,1024]
//   [8M,14M)  wqkv bf16 3x[1024,1024]
//   [14M,16M) wpb  bf16 [1024,1024]
//   [16M,40M) qkv  bf16 q,k:[B,H,T,64], v:[B,H,64,T]
//   [40M,48M) yb   bf16 [4096,1024]
// ---------------------------------------------------------------------------

typedef __attribute__((ext_vector_type(8))) short bf16x8;
typedef __attribute__((ext_vector_type(8))) unsigned short u16x8;
typedef __attribute__((ext_vector_type(4))) float f32x4;

__device__ __forceinline__ float bf2f(unsigned short u) {
  union { unsigned u; float f; } x; x.u = ((unsigned)u) << 16; return x.f;
}
__device__ __forceinline__ unsigned short f2bf(float f) {
  union { float f; unsigned u; } x; x.f = f;
  unsigned r = x.u + 0x7FFFu + ((x.u >> 16) & 1u);  // RNE
  return (unsigned short)(r >> 16);
}

#define GLOAD_LDS16(g, l)                                                     \
  __builtin_amdgcn_global_load_lds(                                           \
      (__attribute__((address_space(1))) void*)(g),                           \
      (__attribute__((address_space(3))) void*)(l), 16, 0, 0)

// ---------------- fp32 -> bf16 (RNE), all 5 tensors in one launch ----------
__global__ void cvt_all(const float* __restrict__ x, const float* __restrict__ Wq,
                        const float* __restrict__ Wk, const float* __restrict__ Wv,
                        const float* __restrict__ Wp, unsigned short* __restrict__ xb,
                        unsigned short* __restrict__ wqkv,
                        unsigned short* __restrict__ wpb) {
  int i = blockIdx.x * 256 + threadIdx.x;  // grid covers exactly 2097152
  const float* src;
  unsigned short* dst;
  int off;
  if (i < 1048576)      { src = x;  dst = xb;             off = i; }
  else if (i < 1310720) { src = Wq; dst = wqkv;           off = i - 1048576; }
  else if (i < 1572864) { src = Wk; dst = wqkv + 1048576; off = i - 1310720; }
  else if (i < 1835008) { src = Wv; dst = wqkv + 2097152; off = i - 1572864; }
  else                  { src = Wp; dst = wpb;            off = i - 1835008; }
  float4 v = ((const float4*)src)[off];
  ushort4 o;
  o.x = f2bf(v.x); o.y = f2bf(v.y); o.z = f2bf(v.z); o.w = f2bf(v.w);
  ((ushort4*)dst)[off] = o;
}

// ---------------- bf16 GEMM: C[m][n] = sum_k A[m][k]*W[n][k] + bias[n] -----
// 128x128 tile, BK=64 via two 32-col slabs (row stride 64B preserved for
// global_load_lds), 256 threads (4 waves, each 64x64). 16 barriers total.
// MODE 0: fp32 row-major out (ld=1024).
// MODE 1: bf16; proj 0/1 (q/k) -> [b,h,t,d]; proj 2 (v) -> [b,h,d,t];
//         coalesced epilogue via per-wave 8KB LDS repack.
template <int MODE>
__global__ __launch_bounds__(256) void gemm_bt(
    const unsigned short* __restrict__ A, const unsigned short* __restrict__ Wall,
    const float* __restrict__ b0, const float* __restrict__ b1,
    const float* __restrict__ b2, void* __restrict__ outp) {
  constexpr int K = 1024;
  // 4 slabs x 8KB: A-slab0, A-slab1, B-slab0, B-slab1 (each 128 rows x 64B)
  __shared__ __align__(16) unsigned short L[4][128 * 32];
  int tid = threadIdx.x;
  int m0 = blockIdx.x * 128;
  int n0;
  const unsigned short* W;
  const float* bias;
  void* out;
  int proj = 0;
  if (MODE == 1) {
    proj = blockIdx.y >> 3;
    n0 = (blockIdx.y & 7) * 128;
    W = Wall + (size_t)proj * (K * 1024);
    bias = (proj == 0) ? b0 : ((proj == 1) ? b1 : b2);
    out = (void*)((unsigned short*)outp + (size_t)proj * 4194304);
  } else {
    n0 = blockIdx.y * 128;
    W = Wall;
    bias = b0;
    out = outp;
  }
  int w = tid >> 6, lane = tid & 63;
  int wm = (w >> 1) * 64, wn = (w & 1) * 64;
  int lm = lane & 15, quad = lane >> 4;

  f32x4 acc[4][4];
#pragma unroll
  for (int mi = 0; mi < 4; ++mi)
#pragma unroll
    for (int ni = 0; ni < 4; ++ni) acc[mi][ni] = (f32x4){0.f, 0.f, 0.f, 0.f};

  // staging: per slab 8KB = 256 thr x 16B x 2 calls
  int o0 = tid * 16, o1 = o0 + 4096;
  int r0 = o0 >> 6, cb0 = o0 & 63;
  int r1 = o1 >> 6, cb1 = o1 & 63;
  const char* a0 = (const char*)A + (size_t)(m0 + r0) * (K * 2) + cb0;
  const char* a1 = (const char*)A + (size_t)(m0 + r1) * (K * 2) + cb1;
  const char* w0 = (const char*)W + (size_t)(n0 + r0) * (K * 2) + cb0;
  const char* w1 = (const char*)W + (size_t)(n0 + r1) * (K * 2) + cb1;
  char* lA0 = (char*)L[0];
  char* lA1 = (char*)L[1];
  char* lB0 = (char*)L[2];
  char* lB1 = (char*)L[3];

  for (int k0 = 0; k0 < K; k0 += 64) {
    int kb = k0 * 2;
    GLOAD_LDS16(a0 + kb, lA0 + o0);
    GLOAD_LDS16(a1 + kb, lA0 + o1);
    GLOAD_LDS16(a0 + kb + 64, lA1 + o0);
    GLOAD_LDS16(a1 + kb + 64, lA1 + o1);
    GLOAD_LDS16(w0 + kb, lB0 + o0);
    GLOAD_LDS16(w1 + kb, lB0 + o1);
    GLOAD_LDS16(w0 + kb + 64, lB1 + o0);
    GLOAD_LDS16(w1 + kb + 64, lB1 + o1);
    __syncthreads();
#pragma unroll
    for (int s = 0; s < 2; ++s) {
      const unsigned short* As = L[s];
      const unsigned short* Bs = L[2 + s];
      bf16x8 af[4], bfv[4];
#pragma unroll
      for (int mi = 0; mi < 4; ++mi)
        af[mi] = *(const bf16x8*)(As + (wm + mi * 16 + lm) * 32 + quad * 8);
#pragma unroll
      for (int ni = 0; ni < 4; ++ni)
        bfv[ni] = *(const bf16x8*)(Bs + (wn + ni * 16 + lm) * 32 + quad * 8);
#pragma unroll
      for (int mi = 0; mi < 4; ++mi)
#pragma unroll
        for (int ni = 0; ni < 4; ++ni)
          acc[mi][ni] = __builtin_amdgcn_mfma_f32_16x16x32_bf16(
              af[mi], bfv[ni], acc[mi][ni], 0, 0, 0);
    }
    __syncthreads();
  }
  // epilogue: C/D layout col=lane&15, row=quad*4+reg
  if (MODE == 0) {
#pragma unroll
    for (int mi = 0; mi < 4; ++mi) {
#pragma unroll
      for (int ni = 0; ni < 4; ++ni) {
        int gn = n0 + wn + ni * 16 + lm;
        float bv = bias[gn];
#pragma unroll
        for (int r = 0; r < 4; ++r) {
          int gm = m0 + wm + mi * 16 + quad * 4 + r;
          ((float*)out)[(size_t)gm * 1024 + gn] = acc[mi][ni][r] + bv;
        }
      }
    }
  } else {
    // per-wave 8KB repack region (slabs are dead after final barrier)
    unsigned short* R = &L[0][0] + w * 4096;
    int bb = (m0 + wm) >> 11, tt0 = (m0 + wm) & 2047;
    int hh = (n0 + wn) >> 6;  // wave's 64 n-cols = exactly one head
#pragma unroll
    for (int mi = 0; mi < 4; ++mi) {
#pragma unroll
      for (int ni = 0; ni < 4; ++ni) {
        float bv = bias[(size_t)(n0 + wn + ni * 16 + lm)];
#pragma unroll
        for (int r = 0; r < 4; ++r) {
          unsigned short val = f2bf(acc[mi][ni][r] + bv);
          int ml = mi * 16 + quad * 4 + r;  // local t
          int nl = ni * 16 + lm;            // local d
          if (proj == 2) R[nl * 64 + ml] = val;  // transpose for V
          else           R[ml * 64 + nl] = val;
        }
      }
    }
    // no barrier needed: region is wave-private (compiler orders ds ops)
    if (proj == 2) {
      unsigned short* vb =
          (unsigned short*)out + (((size_t)bb * 16 + hh) * 64) * 2048 + tt0;
#pragma unroll
      for (int it = 0; it < 8; ++it) {
        int v = it * 64 + lane;
        int r = v >> 3, c8 = v & 7;
        *(u16x8*)(vb + (size_t)r * 2048 + c8 * 8) = *(const u16x8*)(R + v * 8);
      }
    } else {
      unsigned short* qb =
          (unsigned short*)out + (((size_t)bb * 16 + hh) * 2048 + tt0) * 64;
#pragma unroll
      for (int it = 0; it < 8; ++it) {
        int v = it * 64 + lane;
        *(u16x8*)(qb + v * 8) = *(const u16x8*)(R + v * 8);
      }
    }
  }
}

// ---------------- banded MFMA flash attention ------------------------------
// 1 block = 64 queries, 4 waves x 16 queries, ZERO barriers.
// Per 64-key chunk: S = Q K^T via 8 mfma_16x16x32_bf16 (frags straight from
// global, L1/L2-hot), in-register softmax (no max-sub: s~N(0,1)), P -> LDS
// (wave-private rows, stride 72 for bank spread) -> A-frags -> PV via 8 MFMA.
// Vt is stored [b,h,d,t] so V B-frags are contiguous global reads.
__global__ __launch_bounds__(256) void attn_band_mfma(
    const unsigned short* __restrict__ qb, const unsigned short* __restrict__ kb,
    const unsigned short* __restrict__ vtg, unsigned short* __restrict__ yb) {
  __shared__ __align__(16) unsigned short Ps[64 * 72];
  int bid = blockIdx.x;
  int qt = bid & 31, h = (bid >> 5) & 15, b = bid >> 9;
  int q0b = qt * 64;
  int tid = threadIdx.x;
  int w = tid >> 6, lane = tid & 63;
  int m = lane & 15, quad = lane >> 4;
  int wq = w * 16;
  int tq0 = q0b + wq;
  size_t hb = ((size_t)(b * 16 + h)) * (2048 * 64);
  size_t vhb = ((size_t)(b * 16 + h)) * (64 * 2048);

  const unsigned short* qrow = qb + hb + (size_t)(tq0 + m) * 64;
  bf16x8 af0 = *(const bf16x8*)(qrow + quad * 8);
  bf16x8 af1 = *(const bf16x8*)(qrow + 32 + quad * 8);

  f32x4 oacc[4];
#pragma unroll
  for (int di = 0; di < 4; ++di) oacc[di] = (f32x4){0.f, 0.f, 0.f, 0.f};
  float lpart[4] = {0.f, 0.f, 0.f, 0.f};

  int jlo = q0b - 256;
  if (jlo < 0) jlo = 0;
  for (int c0 = jlo; c0 <= q0b; c0 += 64) {
    f32x4 sacc[4];
#pragma unroll
    for (int ni = 0; ni < 4; ++ni) sacc[ni] = (f32x4){0.f, 0.f, 0.f, 0.f};
    const unsigned short* kbase = kb + hb + (size_t)c0 * 64;
#pragma unroll
    for (int ks = 0; ks < 2; ++ks) {
      bf16x8 a = ks ? af1 : af0;
#pragma unroll
      for (int ni = 0; ni < 4; ++ni) {
        bf16x8 bfr =
            *(const bf16x8*)(kbase + (size_t)(ni * 16 + m) * 64 + ks * 32 + quad * 8);
        sacc[ni] = __builtin_amdgcn_mfma_f32_16x16x32_bf16(a, bfr, sacc[ni], 0, 0, 0);
      }
    }
#pragma unroll
    for (int ni = 0; ni < 4; ++ni) {
      int j = c0 + ni * 16 + m;
#pragma unroll
      for (int r = 0; r < 4; ++r) {
        int t = tq0 + quad * 4 + r;
        float e = __expf(sacc[ni][r] * 0.125f);
        e = ((unsigned)(t - j) <= 256u) ? e : 0.f;  // causal + band
        lpart[r] += e;
        Ps[(wq + quad * 4 + r) * 72 + ni * 16 + m] = f2bf(e);
      }
    }
    const unsigned short* vbase = vtg + vhb + c0;
#pragma unroll
    for (int ks = 0; ks < 2; ++ks) {
      bf16x8 a = *(const bf16x8*)(Ps + (wq + m) * 72 + ks * 32 + quad * 8);
#pragma unroll
      for (int di = 0; di < 4; ++di) {
        bf16x8 bfr =
            *(const bf16x8*)(vbase + (size_t)(di * 16 + m) * 2048 + ks * 32 + quad * 8);
        oacc[di] = __builtin_amdgcn_mfma_f32_16x16x32_bf16(a, bfr, oacc[di], 0, 0, 0);
      }
    }
  }
#pragma unroll
  for (int mask = 1; mask <= 8; mask <<= 1)
#pragma unroll
    for (int r = 0; r < 4; ++r) lpart[r] += __shfl_xor(lpart[r], mask, 64);
  float inv[4];
#pragma unroll
  for (int r = 0; r < 4; ++r) inv[r] = 1.f / lpart[r];
#pragma unroll
  for (int di = 0; di < 4; ++di)
#pragma unroll
    for (int r = 0; r < 4; ++r)
      Ps[(wq + quad * 4 + r) * 72 + di * 16 + m] = f2bf(oacc[di][r] * inv[r]);
  size_t orow = (size_t)b * 2048 + tq0;
#pragma unroll
  for (int v2 = 0; v2 < 2; ++v2) {
    int v = v2 * 64 + lane;
    int q = v >> 3, dg = v & 7;
    u16x8 val = *(const u16x8*)(Ps + (wq + q) * 72 + dg * 8);
    *(u16x8*)(yb + (orow + q) * 1024 + h * 64 + dg * 8) = val;
  }
}

// ---------------------------------------------------------------------------
extern "C" void kernel_launch(void* const* d_in, const int* in_sizes, int n_in,
                              void* d_out, int out_size, void* d_ws,
                              size_t ws_size, hipStream_t stream) {
  const float* x  = (const float*)d_in[0];
  const float* Wq = (const float*)d_in[1];
  const float* bq = (const float*)d_in[2];
  const float* Wk = (const float*)d_in[3];
  const float* bk = (const float*)d_in[4];
  const float* Wv = (const float*)d_in[5];
  const float* bv = (const float*)d_in[6];
  const float* Wp = (const float*)d_in[7];
  const float* bp = (const float*)d_in[8];
  float* out = (float*)d_out;

  char* ws = (char*)d_ws;
  unsigned short* xb   = (unsigned short*)(ws);
  unsigned short* wqkv = (unsigned short*)(ws + (8ull << 20));
  unsigned short* wpb  = (unsigned short*)(ws + (14ull << 20));
  unsigned short* qkv  = (unsigned short*)(ws + (16ull << 20));
  unsigned short* yb   = (unsigned short*)(ws + (40ull << 20));

  cvt_all<<<8192, 256, 0, stream>>>(x, Wq, Wk, Wv, Wp, xb, wqkv, wpb);
  gemm_bt<1><<<dim3(32, 24), 256, 0, stream>>>(xb, wqkv, bq, bk, bv, (void*)qkv);
  attn_band_mfma<<<1024, 256, 0, stream>>>(qkv, qkv + 4194304ull,
                                           qkv + 8388608ull, yb);
  gemm_bt<0><<<dim3(32, 8), 256, 0, stream>>>(yb, wpb, bp, nullptr, nullptr,
                                              (void*)out);
}

// Round 4
// 192.477 us; speedup vs baseline: 1.0138x; 1.0138x over previous
//
#include <hip/hip_runtime.h>

// ---------------------------------------------------------------------------
// CausalSelfAttention, banded (band=256), B=2 T=2048 C=1024 H=16 hd=64.
// cvt(fp32->bf16) -> fused QKV bf16-MFMA GEMM (round-2 m97 structure, BK=32,
// V written TRANSPOSED [b,h,d,t]) -> banded MFMA flash attention (no
// barriers, software-pipelined K-prefetch) -> output projection GEMM.
// Workspace layout (bytes):
//   [0,8M)    xb   bf16 [4096,1024]
//   [8M,14M)  wqkv bf16 3x[1024,1024]
//   [14M,16M) wpb  bf16 [1024,1024]
//   [16M,40M) qkv  bf16 q,k:[B,H,T,64], v:[B,H,64,T]
//   [40M,48M) yb   bf16 [4096,1024]
// ---------------------------------------------------------------------------

typedef __attribute__((ext_vector_type(8))) short bf16x8;
typedef __attribute__((ext_vector_type(8))) unsigned short u16x8;
typedef __attribute__((ext_vector_type(4))) float f32x4;

__device__ __forceinline__ float bf2f(unsigned short u) {
  union { unsigned u; float f; } x; x.u = ((unsigned)u) << 16; return x.f;
}
__device__ __forceinline__ unsigned short f2bf(float f) {
  union { float f; unsigned u; } x; x.f = f;
  unsigned r = x.u + 0x7FFFu + ((x.u >> 16) & 1u);  // RNE
  return (unsigned short)(r >> 16);
}

#define GLOAD_LDS16(g, l)                                                     \
  __builtin_amdgcn_global_load_lds(                                           \
      (__attribute__((address_space(1))) void*)(g),                           \
      (__attribute__((address_space(3))) void*)(l), 16, 0, 0)

// ---------------- fp32 -> bf16 (RNE), all 5 tensors in one launch ----------
__global__ void cvt_all(const float* __restrict__ x, const float* __restrict__ Wq,
                        const float* __restrict__ Wk, const float* __restrict__ Wv,
                        const float* __restrict__ Wp, unsigned short* __restrict__ xb,
                        unsigned short* __restrict__ wqkv,
                        unsigned short* __restrict__ wpb) {
  int i = blockIdx.x * 256 + threadIdx.x;  // grid covers exactly 2097152
  const float* src;
  unsigned short* dst;
  int off;
  if (i < 1048576)      { src = x;  dst = xb;             off = i; }
  else if (i < 1310720) { src = Wq; dst = wqkv;           off = i - 1048576; }
  else if (i < 1572864) { src = Wk; dst = wqkv + 1048576; off = i - 1310720; }
  else if (i < 1835008) { src = Wv; dst = wqkv + 2097152; off = i - 1572864; }
  else                  { src = Wp; dst = wpb;            off = i - 1835008; }
  float4 v = ((const float4*)src)[off];
  ushort4 o;
  o.x = f2bf(v.x); o.y = f2bf(v.y); o.z = f2bf(v.z); o.w = f2bf(v.w);
  ((ushort4*)dst)[off] = o;
}

// ---------------- bf16 GEMM: C[m][n] = sum_k A[m][k]*W[n][k] + bias[n] -----
// 128x128 tile, BK=32, 256 threads (4 waves, each 64x64), m97 structure
// (round-2 known-good: 42.5 us QKV). MODE 0: fp32 row-major out.
// MODE 1: bf16 scatter; proj 0/1 (q/k) -> [b,h,t,d]; proj 2 (v) -> [b,h,d,t].
template <int MODE>
__global__ __launch_bounds__(256) void gemm_bt(
    const unsigned short* __restrict__ A, const unsigned short* __restrict__ Wall,
    const float* __restrict__ b0, const float* __restrict__ b1,
    const float* __restrict__ b2, void* __restrict__ outp) {
  constexpr int K = 1024;
  __shared__ __align__(16) unsigned short As[128 * 32];
  __shared__ __align__(16) unsigned short Bs[128 * 32];
  int tid = threadIdx.x;
  int m0 = blockIdx.x * 128;
  int n0;
  const unsigned short* W;
  const float* bias;
  void* out;
  int proj = 0;
  if (MODE == 1) {
    proj = blockIdx.y >> 3;
    n0 = (blockIdx.y & 7) * 128;
    W = Wall + (size_t)proj * (K * 1024);
    bias = (proj == 0) ? b0 : ((proj == 1) ? b1 : b2);
    out = (void*)((unsigned short*)outp + (size_t)proj * 4194304);
  } else {
    n0 = blockIdx.y * 128;
    W = Wall;
    bias = b0;
    out = outp;
  }
  int w = tid >> 6, lane = tid & 63;
  int wm = (w >> 1) * 64, wn = (w & 1) * 64;
  int lm = lane & 15, quad = lane >> 4;

  f32x4 acc[4][4];
#pragma unroll
  for (int mi = 0; mi < 4; ++mi)
#pragma unroll
    for (int ni = 0; ni < 4; ++ni) acc[mi][ni] = (f32x4){0.f, 0.f, 0.f, 0.f};

  int o0 = tid * 16, o1 = o0 + 4096;
  int r0 = o0 >> 6, cb0 = o0 & 63;
  int r1 = o1 >> 6, cb1 = o1 & 63;
  const char* a0 = (const char*)A + (size_t)(m0 + r0) * (K * 2) + cb0;
  const char* a1 = (const char*)A + (size_t)(m0 + r1) * (K * 2) + cb1;
  const char* w0 = (const char*)W + (size_t)(n0 + r0) * (K * 2) + cb0;
  const char* w1 = (const char*)W + (size_t)(n0 + r1) * (K * 2) + cb1;
  char* lA = (char*)As;
  char* lB = (char*)Bs;

  for (int k0 = 0; k0 < K; k0 += 32) {
    GLOAD_LDS16(a0 + k0 * 2, lA + o0);
    GLOAD_LDS16(a1 + k0 * 2, lA + o1);
    GLOAD_LDS16(w0 + k0 * 2, lB + o0);
    GLOAD_LDS16(w1 + k0 * 2, lB + o1);
    __syncthreads();
    bf16x8 af[4], bfv[4];
#pragma unroll
    for (int mi = 0; mi < 4; ++mi)
      af[mi] = *(const bf16x8*)(As + (wm + mi * 16 + lm) * 32 + quad * 8);
#pragma unroll
    for (int ni = 0; ni < 4; ++ni)
      bfv[ni] = *(const bf16x8*)(Bs + (wn + ni * 16 + lm) * 32 + quad * 8);
#pragma unroll
    for (int mi = 0; mi < 4; ++mi)
#pragma unroll
      for (int ni = 0; ni < 4; ++ni)
        acc[mi][ni] = __builtin_amdgcn_mfma_f32_16x16x32_bf16(
            af[mi], bfv[ni], acc[mi][ni], 0, 0, 0);
    __syncthreads();
  }
  // epilogue: C/D layout col=lane&15, row=quad*4+reg
#pragma unroll
  for (int mi = 0; mi < 4; ++mi) {
#pragma unroll
    for (int ni = 0; ni < 4; ++ni) {
      int gn = n0 + wn + ni * 16 + lm;
      float bv = bias[gn];
#pragma unroll
      for (int r = 0; r < 4; ++r) {
        int gm = m0 + wm + mi * 16 + quad * 4 + r;
        float val = acc[mi][ni][r] + bv;
        if (MODE == 0) {
          ((float*)out)[(size_t)gm * 1024 + gn] = val;
        } else {
          int bb = gm >> 11, tt = gm & 2047;
          int hh = gn >> 6, dd = gn & 63;
          size_t idx;
          if (proj == 2)  // V transposed: [b,h,d,t]
            idx = (((size_t)bb * 16 + hh) * 64 + dd) * 2048 + tt;
          else            // Q,K: [b,h,t,d]
            idx = (((size_t)bb * 16 + hh) * 2048 + tt) * 64 + dd;
          ((unsigned short*)out)[idx] = f2bf(val);
        }
      }
    }
  }
}

// ---------------- banded MFMA flash attention, K-prefetch pipeline ---------
// 1 block = 64 queries, 4 waves x 16 queries, ZERO barriers.
// Pipeline per 64-key chunk: [V-cur loads issue] -> S=QK^T (consumes kf) ->
// [K-next loads issue into kf, clamped addr on last iter] -> softmax ->
// P->LDS roundtrip -> PV. K/V latency (~200cyc L2) hides under the ~250cyc
// compute+LDS chain. launch_bounds(256,4) caps VGPR at 128 (peak ~116).
__global__ __launch_bounds__(256, 4) void attn_band_mfma(
    const unsigned short* __restrict__ qb, const unsigned short* __restrict__ kb,
    const unsigned short* __restrict__ vtg, unsigned short* __restrict__ yb) {
  __shared__ __align__(16) unsigned short Ps[64 * 72];
  int bid = blockIdx.x;
  int qt = bid & 31, h = (bid >> 5) & 15, b = bid >> 9;
  int q0b = qt * 64;
  int tid = threadIdx.x;
  int w = tid >> 6, lane = tid & 63;
  int m = lane & 15, quad = lane >> 4;
  int wq = w * 16;
  int tq0 = q0b + wq;
  size_t hb = ((size_t)(b * 16 + h)) * (2048 * 64);
  size_t vhb = ((size_t)(b * 16 + h)) * (64 * 2048);
  const unsigned short* kbase = kb + hb;
  const unsigned short* vbase = vtg + vhb;

  const unsigned short* qrow = qb + hb + (size_t)(tq0 + m) * 64;
  bf16x8 af0 = *(const bf16x8*)(qrow + quad * 8);
  bf16x8 af1 = *(const bf16x8*)(qrow + 32 + quad * 8);

  f32x4 oacc[4];
#pragma unroll
  for (int di = 0; di < 4; ++di) oacc[di] = (f32x4){0.f, 0.f, 0.f, 0.f};
  float lpart[4] = {0.f, 0.f, 0.f, 0.f};

  int jlo = q0b - 256;
  if (jlo < 0) jlo = 0;

  // prologue: K-frags for first chunk
  bf16x8 kf[8];
#pragma unroll
  for (int ni = 0; ni < 4; ++ni) {
    const unsigned short* kr = kbase + (size_t)(jlo + ni * 16 + m) * 64 + quad * 8;
    kf[ni * 2] = *(const bf16x8*)(kr);
    kf[ni * 2 + 1] = *(const bf16x8*)(kr + 32);
  }

  for (int c0 = jlo; c0 <= q0b; c0 += 64) {
    // ---- V-current loads issue first (consumed last) ----------------------
    bf16x8 vf[8];
#pragma unroll
    for (int di = 0; di < 4; ++di) {
      const unsigned short* vr = vbase + (size_t)(di * 16 + m) * 2048 + c0 + quad * 8;
      vf[di * 2] = *(const bf16x8*)(vr);
      vf[di * 2 + 1] = *(const bf16x8*)(vr + 32);
    }
    // ---- S = Q K^T (kf resident from prefetch) ----------------------------
    f32x4 sacc[4];
#pragma unroll
    for (int ni = 0; ni < 4; ++ni) sacc[ni] = (f32x4){0.f, 0.f, 0.f, 0.f};
#pragma unroll
    for (int ni = 0; ni < 4; ++ni) {
      sacc[ni] = __builtin_amdgcn_mfma_f32_16x16x32_bf16(af0, kf[ni * 2], sacc[ni], 0, 0, 0);
      sacc[ni] = __builtin_amdgcn_mfma_f32_16x16x32_bf16(af1, kf[ni * 2 + 1], sacc[ni], 0, 0, 0);
    }
    // ---- K-next prefetch (clamped on last iter; data unused then) ---------
    {
      int cn = c0 + 64;
      if (cn > q0b) cn = q0b;
#pragma unroll
      for (int ni = 0; ni < 4; ++ni) {
        const unsigned short* kr = kbase + (size_t)(cn + ni * 16 + m) * 64 + quad * 8;
        kf[ni * 2] = *(const bf16x8*)(kr);
        kf[ni * 2 + 1] = *(const bf16x8*)(kr + 32);
      }
    }
    // ---- softmax piece: mask, exp, row sums, P -> LDS (bf16) --------------
#pragma unroll
    for (int ni = 0; ni < 4; ++ni) {
      int j = c0 + ni * 16 + m;
#pragma unroll
      for (int r = 0; r < 4; ++r) {
        int t = tq0 + quad * 4 + r;
        float e = __expf(sacc[ni][r] * 0.125f);
        e = ((unsigned)(t - j) <= 256u) ? e : 0.f;  // causal + band
        lpart[r] += e;
        Ps[(wq + quad * 4 + r) * 72 + ni * 16 + m] = f2bf(e);
      }
    }
    // ---- O += P V ---------------------------------------------------------
#pragma unroll
    for (int ks = 0; ks < 2; ++ks) {
      bf16x8 a = *(const bf16x8*)(Ps + (wq + m) * 72 + ks * 32 + quad * 8);
#pragma unroll
      for (int di = 0; di < 4; ++di)
        oacc[di] = __builtin_amdgcn_mfma_f32_16x16x32_bf16(
            a, vf[di * 2 + ks], oacc[di], 0, 0, 0);
    }
  }
#pragma unroll
  for (int mask = 1; mask <= 8; mask <<= 1)
#pragma unroll
    for (int r = 0; r < 4; ++r) lpart[r] += __shfl_xor(lpart[r], mask, 64);
  float inv[4];
#pragma unroll
  for (int r = 0; r < 4; ++r) inv[r] = 1.f / lpart[r];
#pragma unroll
  for (int di = 0; di < 4; ++di)
#pragma unroll
    for (int r = 0; r < 4; ++r)
      Ps[(wq + quad * 4 + r) * 72 + di * 16 + m] = f2bf(oacc[di][r] * inv[r]);
  size_t orow = (size_t)b * 2048 + tq0;
#pragma unroll
  for (int v2 = 0; v2 < 2; ++v2) {
    int v = v2 * 64 + lane;
    int q = v >> 3, dg = v & 7;
    u16x8 val = *(const u16x8*)(Ps + (wq + q) * 72 + dg * 8);
    *(u16x8*)(yb + (orow + q) * 1024 + h * 64 + dg * 8) = val;
  }
}

// ---------------------------------------------------------------------------
extern "C" void kernel_launch(void* const* d_in, const int* in_sizes, int n_in,
                              void* d_out, int out_size, void* d_ws,
                              size_t ws_size, hipStream_t stream) {
  const float* x  = (const float*)d_in[0];
  const float* Wq = (const float*)d_in[1];
  const float* bq = (const float*)d_in[2];
  const float* Wk = (const float*)d_in[3];
  const float* bk = (const float*)d_in[4];
  const float* Wv = (const float*)d_in[5];
  const float* bv = (const float*)d_in[6];
  const float* Wp = (const float*)d_in[7];
  const float* bp = (const float*)d_in[8];
  float* out = (float*)d_out;

  char* ws = (char*)d_ws;
  unsigned short* xb   = (unsigned short*)(ws);
  unsigned short* wqkv = (unsigned short*)(ws + (8ull << 20));
  unsigned short* wpb  = (unsigned short*)(ws + (14ull << 20));
  unsigned short* qkv  = (unsigned short*)(ws + (16ull << 20));
  unsigned short* yb   = (unsigned short*)(ws + (40ull << 20));

  cvt_all<<<8192, 256, 0, stream>>>(x, Wq, Wk, Wv, Wp, xb, wqkv, wpb);
  gemm_bt<1><<<dim3(32, 24), 256, 0, stream>>>(xb, wqkv, bq, bk, bv, (void*)qkv);
  attn_band_mfma<<<1024, 256, 0, stream>>>(qkv, qkv + 4194304ull,
                                           qkv + 8388608ull, yb);
  gemm_bt<0><<<dim3(32, 8), 256, 0, stream>>>(yb, wpb, bp, nullptr, nullptr,
                                              (void*)out);
}

// Round 5
// 169.884 us; speedup vs baseline: 1.1486x; 1.1330x over previous
//
#include <hip/hip_runtime.h>

// ---------------------------------------------------------------------------
// CausalSelfAttention, banded (band=256), B=2 T=2048 C=1024 H=16 hd=64.
// cvt(fp32->bf16) -> fused QKV bf16-MFMA GEMM (m97 structure, BK=32, V
// written TRANSPOSED [b,h,d,t]) -> banded MFMA flash attention with
// global_load_lds K/V chunk staging (batched DMA, stride-144 swizzled LDS
// rows for conflict-free ds_read_b128 frags) -> output projection GEMM.
// Workspace layout (bytes):
//   [0,8M)    xb   bf16 [4096,1024]
//   [8M,14M)  wqkv bf16 3x[1024,1024]
//   [14M,16M) wpb  bf16 [1024,1024]
//   [16M,40M) qkv  bf16 q,k:[B,H,T,64], v:[B,H,64,T]
//   [40M,48M) yb   bf16 [4096,1024]
// ---------------------------------------------------------------------------

typedef __attribute__((ext_vector_type(8))) short bf16x8;
typedef __attribute__((ext_vector_type(8))) unsigned short u16x8;
typedef __attribute__((ext_vector_type(4))) float f32x4;

__device__ __forceinline__ float bf2f(unsigned short u) {
  union { unsigned u; float f; } x; x.u = ((unsigned)u) << 16; return x.f;
}
__device__ __forceinline__ unsigned short f2bf(float f) {
  union { float f; unsigned u; } x; x.f = f;
  unsigned r = x.u + 0x7FFFu + ((x.u >> 16) & 1u);  // RNE
  return (unsigned short)(r >> 16);
}

#define GLOAD_LDS16(g, l)                                                     \
  __builtin_amdgcn_global_load_lds(                                           \
      (__attribute__((address_space(1))) void*)(g),                           \
      (__attribute__((address_space(3))) void*)(l), 16, 0, 0)

// ---------------- fp32 -> bf16 (RNE), all 5 tensors in one launch ----------
__global__ void cvt_all(const float* __restrict__ x, const float* __restrict__ Wq,
                        const float* __restrict__ Wk, const float* __restrict__ Wv,
                        const float* __restrict__ Wp, unsigned short* __restrict__ xb,
                        unsigned short* __restrict__ wqkv,
                        unsigned short* __restrict__ wpb) {
  int i = blockIdx.x * 256 + threadIdx.x;  // grid covers exactly 2097152
  const float* src;
  unsigned short* dst;
  int off;
  if (i < 1048576)      { src = x;  dst = xb;             off = i; }
  else if (i < 1310720) { src = Wq; dst = wqkv;           off = i - 1048576; }
  else if (i < 1572864) { src = Wk; dst = wqkv + 1048576; off = i - 1310720; }
  else if (i < 1835008) { src = Wv; dst = wqkv + 2097152; off = i - 1572864; }
  else                  { src = Wp; dst = wpb;            off = i - 1835008; }
  float4 v = ((const float4*)src)[off];
  ushort4 o;
  o.x = f2bf(v.x); o.y = f2bf(v.y); o.z = f2bf(v.z); o.w = f2bf(v.w);
  ((ushort4*)dst)[off] = o;
}

// ---------------- bf16 GEMM: C[m][n] = sum_k A[m][k]*W[n][k] + bias[n] -----
// 128x128 tile, BK=32, 256 threads (4 waves, each 64x64), m97 structure
// (known-good: 42.5 us QKV). MODE 0: fp32 row-major out.
// MODE 1: bf16 scatter; proj 0/1 (q/k) -> [b,h,t,d]; proj 2 (v) -> [b,h,d,t].
template <int MODE>
__global__ __launch_bounds__(256) void gemm_bt(
    const unsigned short* __restrict__ A, const unsigned short* __restrict__ Wall,
    const float* __restrict__ b0, const float* __restrict__ b1,
    const float* __restrict__ b2, void* __restrict__ outp) {
  constexpr int K = 1024;
  __shared__ __align__(16) unsigned short As[128 * 32];
  __shared__ __align__(16) unsigned short Bs[128 * 32];
  int tid = threadIdx.x;
  int m0 = blockIdx.x * 128;
  int n0;
  const unsigned short* W;
  const float* bias;
  void* out;
  int proj = 0;
  if (MODE == 1) {
    proj = blockIdx.y >> 3;
    n0 = (blockIdx.y & 7) * 128;
    W = Wall + (size_t)proj * (K * 1024);
    bias = (proj == 0) ? b0 : ((proj == 1) ? b1 : b2);
    out = (void*)((unsigned short*)outp + (size_t)proj * 4194304);
  } else {
    n0 = blockIdx.y * 128;
    W = Wall;
    bias = b0;
    out = outp;
  }
  int w = tid >> 6, lane = tid & 63;
  int wm = (w >> 1) * 64, wn = (w & 1) * 64;
  int lm = lane & 15, quad = lane >> 4;

  f32x4 acc[4][4];
#pragma unroll
  for (int mi = 0; mi < 4; ++mi)
#pragma unroll
    for (int ni = 0; ni < 4; ++ni) acc[mi][ni] = (f32x4){0.f, 0.f, 0.f, 0.f};

  int o0 = tid * 16, o1 = o0 + 4096;
  int r0 = o0 >> 6, cb0 = o0 & 63;
  int r1 = o1 >> 6, cb1 = o1 & 63;
  const char* a0 = (const char*)A + (size_t)(m0 + r0) * (K * 2) + cb0;
  const char* a1 = (const char*)A + (size_t)(m0 + r1) * (K * 2) + cb1;
  const char* w0 = (const char*)W + (size_t)(n0 + r0) * (K * 2) + cb0;
  const char* w1 = (const char*)W + (size_t)(n0 + r1) * (K * 2) + cb1;
  char* lA = (char*)As;
  char* lB = (char*)Bs;

  for (int k0 = 0; k0 < K; k0 += 32) {
    GLOAD_LDS16(a0 + k0 * 2, lA + o0);
    GLOAD_LDS16(a1 + k0 * 2, lA + o1);
    GLOAD_LDS16(w0 + k0 * 2, lB + o0);
    GLOAD_LDS16(w1 + k0 * 2, lB + o1);
    __syncthreads();
    bf16x8 af[4], bfv[4];
#pragma unroll
    for (int mi = 0; mi < 4; ++mi)
      af[mi] = *(const bf16x8*)(As + (wm + mi * 16 + lm) * 32 + quad * 8);
#pragma unroll
    for (int ni = 0; ni < 4; ++ni)
      bfv[ni] = *(const bf16x8*)(Bs + (wn + ni * 16 + lm) * 32 + quad * 8);
#pragma unroll
    for (int mi = 0; mi < 4; ++mi)
#pragma unroll
      for (int ni = 0; ni < 4; ++ni)
        acc[mi][ni] = __builtin_amdgcn_mfma_f32_16x16x32_bf16(
            af[mi], bfv[ni], acc[mi][ni], 0, 0, 0);
    __syncthreads();
  }
  // epilogue: C/D layout col=lane&15, row=quad*4+reg
#pragma unroll
  for (int mi = 0; mi < 4; ++mi) {
#pragma unroll
    for (int ni = 0; ni < 4; ++ni) {
      int gn = n0 + wn + ni * 16 + lm;
      float bv = bias[gn];
#pragma unroll
      for (int r = 0; r < 4; ++r) {
        int gm = m0 + wm + mi * 16 + quad * 4 + r;
        float val = acc[mi][ni][r] + bv;
        if (MODE == 0) {
          ((float*)out)[(size_t)gm * 1024 + gn] = val;
        } else {
          int bb = gm >> 11, tt = gm & 2047;
          int hh = gn >> 6, dd = gn & 63;
          size_t idx;
          if (proj == 2)  // V transposed: [b,h,d,t]
            idx = (((size_t)bb * 16 + hh) * 64 + dd) * 2048 + tt;
          else            // Q,K: [b,h,t,d]
            idx = (((size_t)bb * 16 + hh) * 2048 + tt) * 64 + dd;
          ((unsigned short*)out)[idx] = f2bf(val);
        }
      }
    }
  }
}

// ---------------- banded MFMA flash attention, LDS-DMA staging -------------
// 1 block = 64 queries, 4 waves x 16 queries. Per 64-key chunk, K (64x64)
// and V (64 d-rows x 64 keys, from [b,h,d,t]) are staged via global_load_lds
// into stride-144B LDS rows: the DMA's global side is a per-lane gather
// (slot s -> row s/9, col s%9; col 8 = pad fetches row base harmlessly), so
// rows get +16B padding WITHOUT violating the lane*16 LDS-contiguity rule.
// Frag ds_read_b128 at (row*72 + slab*32 + quad*8) shorts then spreads banks
// ((4*(m+quad)+16*slab) mod 32 -> 2-way max, free). Batched DMA = one vmcnt
// drain per chunk instead of ~12 serialized HBM latencies (round-4 failure:
// compiler sank register prefetches to use sites, VGPR_Count=48 proved it).
__global__ __launch_bounds__(256) void attn_band_mfma(
    const unsigned short* __restrict__ qb, const unsigned short* __restrict__ kb,
    const unsigned short* __restrict__ vtg, unsigned short* __restrict__ yb) {
  __shared__ __align__(16) unsigned short Kb[64 * 72];
  __shared__ __align__(16) unsigned short Vb[64 * 72];
  __shared__ __align__(16) unsigned short Ps[64 * 72];
  int bid = blockIdx.x;
  int qt = bid & 31, h = (bid >> 5) & 15, b = bid >> 9;
  int q0b = qt * 64;
  int tid = threadIdx.x;
  int lane = tid & 63;
  int w = tid >> 6;
  int m = lane & 15, quad = lane >> 4;
  int wq = w * 16;
  int tq0 = q0b + wq;
  size_t hb = ((size_t)(b * 16 + h)) * (2048 * 64);
  size_t vhb = ((size_t)(b * 16 + h)) * (64 * 2048);
  const char* kgb = (const char*)(kb + hb);    // K rows: 128 B stride
  const char* vgb = (const char*)(vtg + vhb);  // Vt rows: 4096 B stride

  // DMA slot precompute: slots 0..575 cover 64 rows x 9 slots(16B); slot%9==8
  // is LDS pad (global addr redirected to row base). This thread handles
  // slots tid, tid+256, and (tail, tid<128) 512+(tid&63).
  int sA = tid, sB = tid + 256, sC = 512 + (tid & 63);
  int rA = sA / 9, kA = sA - rA * 9;
  int rB = sB / 9, kB = sB - rB * 9;
  int rC = sC / 9, kC = sC - rC * 9;
  int okA = (kA < 8) ? kA : 0, okB = (kB < 8) ? kB : 0, okC = (kC < 8) ? kC : 0;
  int offKA = rA * 128 + okA * 16, offVA = rA * 4096 + okA * 16;
  int offKB = rB * 128 + okB * 16, offVB = rB * 4096 + okB * 16;
  int offKC = rC * 128 + okC * 16, offVC = rC * 4096 + okC * 16;
  char* KbB = (char*)Kb;
  char* VbB = (char*)Vb;

  // Q A-frags (held all kernel; one-time loads)
  const unsigned short* qrow = qb + hb + (size_t)(tq0 + m) * 64;
  bf16x8 af0 = *(const bf16x8*)(qrow + quad * 8);
  bf16x8 af1 = *(const bf16x8*)(qrow + 32 + quad * 8);

  f32x4 oacc[4];
#pragma unroll
  for (int di = 0; di < 4; ++di) oacc[di] = (f32x4){0.f, 0.f, 0.f, 0.f};
  float lpart[4] = {0.f, 0.f, 0.f, 0.f};

  int jlo = q0b - 256;
  if (jlo < 0) jlo = 0;
  for (int c0 = jlo; c0 <= q0b; c0 += 64) {
    const char* kg = kgb + (size_t)c0 * 128;  // chunk row base (K: key rows)
    const char* vg = vgb + (size_t)c0 * 2;    // chunk col base (Vt: d rows)
    __syncthreads();  // previous chunk fully consumed before overwrite
    GLOAD_LDS16(kg + offKA, KbB + sA * 16);
    GLOAD_LDS16(kg + offKB, KbB + sB * 16);
    GLOAD_LDS16(vg + offVA, VbB + sA * 16);
    GLOAD_LDS16(vg + offVB, VbB + sB * 16);
    if (tid < 128) {  // tail: wave0 -> K slots 512.., wave1 -> V slots 512..
      const char* g = (tid < 64) ? (kg + offKC) : (vg + offVC);
      char* l = ((tid < 64) ? KbB : VbB) + sC * 16;
      GLOAD_LDS16(g, l);
    }
    __syncthreads();  // vmcnt drain: chunk resident

    // ---- S = Q K^T --------------------------------------------------------
    f32x4 sacc[4];
#pragma unroll
    for (int ni = 0; ni < 4; ++ni) sacc[ni] = (f32x4){0.f, 0.f, 0.f, 0.f};
#pragma unroll
    for (int ni = 0; ni < 4; ++ni) {
      bf16x8 k0 = *(const bf16x8*)(Kb + (ni * 16 + m) * 72 + quad * 8);
      bf16x8 k1 = *(const bf16x8*)(Kb + (ni * 16 + m) * 72 + 32 + quad * 8);
      sacc[ni] = __builtin_amdgcn_mfma_f32_16x16x32_bf16(af0, k0, sacc[ni], 0, 0, 0);
      sacc[ni] = __builtin_amdgcn_mfma_f32_16x16x32_bf16(af1, k1, sacc[ni], 0, 0, 0);
    }
    // ---- softmax piece: mask, exp, row sums, P -> LDS (bf16) --------------
#pragma unroll
    for (int ni = 0; ni < 4; ++ni) {
      int j = c0 + ni * 16 + m;
#pragma unroll
      for (int r = 0; r < 4; ++r) {
        int t = tq0 + quad * 4 + r;
        float e = __expf(sacc[ni][r] * 0.125f);
        e = ((unsigned)(t - j) <= 256u) ? e : 0.f;  // causal + band
        lpart[r] += e;
        Ps[(wq + quad * 4 + r) * 72 + ni * 16 + m] = f2bf(e);
      }
    }
    // ---- O += P V ---------------------------------------------------------
#pragma unroll
    for (int ks = 0; ks < 2; ++ks) {
      bf16x8 a = *(const bf16x8*)(Ps + (wq + m) * 72 + ks * 32 + quad * 8);
#pragma unroll
      for (int di = 0; di < 4; ++di) {
        bf16x8 vfr = *(const bf16x8*)(Vb + (di * 16 + m) * 72 + ks * 32 + quad * 8);
        oacc[di] = __builtin_amdgcn_mfma_f32_16x16x32_bf16(a, vfr, oacc[di], 0, 0, 0);
      }
    }
  }
  // ---- finalize -----------------------------------------------------------
#pragma unroll
  for (int mask = 1; mask <= 8; mask <<= 1)
#pragma unroll
    for (int r = 0; r < 4; ++r) lpart[r] += __shfl_xor(lpart[r], mask, 64);
  float inv[4];
#pragma unroll
  for (int r = 0; r < 4; ++r) inv[r] = 1.f / lpart[r];
#pragma unroll
  for (int di = 0; di < 4; ++di)
#pragma unroll
    for (int r = 0; r < 4; ++r)
      Ps[(wq + quad * 4 + r) * 72 + di * 16 + m] = f2bf(oacc[di][r] * inv[r]);
  size_t orow = (size_t)b * 2048 + tq0;
#pragma unroll
  for (int v2 = 0; v2 < 2; ++v2) {
    int v = v2 * 64 + lane;
    int q = v >> 3, dg = v & 7;
    u16x8 val = *(const u16x8*)(Ps + (wq + q) * 72 + dg * 8);
    *(u16x8*)(yb + (orow + q) * 1024 + h * 64 + dg * 8) = val;
  }
}

// ---------------------------------------------------------------------------
extern "C" void kernel_launch(void* const* d_in, const int* in_sizes, int n_in,
                              void* d_out, int out_size, void* d_ws,
                              size_t ws_size, hipStream_t stream) {
  const float* x  = (const float*)d_in[0];
  const float* Wq = (const float*)d_in[1];
  const float* bq = (const float*)d_in[2];
  const float* Wk = (const float*)d_in[3];
  const float* bk = (const float*)d_in[4];
  const float* Wv = (const float*)d_in[5];
  const float* bv = (const float*)d_in[6];
  const float* Wp = (const float*)d_in[7];
  const float* bp = (const float*)d_in[8];
  float* out = (float*)d_out;

  char* ws = (char*)d_ws;
  unsigned short* xb   = (unsigned short*)(ws);
  unsigned short* wqkv = (unsigned short*)(ws + (8ull << 20));
  unsigned short* wpb  = (unsigned short*)(ws + (14ull << 20));
  unsigned short* qkv  = (unsigned short*)(ws + (16ull << 20));
  unsigned short* yb   = (unsigned short*)(ws + (40ull << 20));

  cvt_all<<<8192, 256, 0, stream>>>(x, Wq, Wk, Wv, Wp, xb, wqkv, wpb);
  gemm_bt<1><<<dim3(32, 24), 256, 0, stream>>>(xb, wqkv, bq, bk, bv, (void*)qkv);
  attn_band_mfma<<<1024, 256, 0, stream>>>(qkv, qkv + 4194304ull,
                                           qkv + 8388608ull, yb);
  gemm_bt<0><<<dim3(32, 8), 256, 0, stream>>>(yb, wpb, bp, nullptr, nullptr,
                                              (void*)out);
}

// Round 6
// 166.703 us; speedup vs baseline: 1.1705x; 1.0191x over previous
//
#include <hip/hip_runtime.h>

// ---------------------------------------------------------------------------
// CausalSelfAttention, banded (band=256), B=2 T=2048 C=1024 H=16 hd=64.
// cvt(fp32->bf16) -> fused QKV bf16-MFMA GEMM (m97 structure, BK=32, V
// written TRANSPOSED [b,h,d,t]) -> banded MFMA flash attention with
// DOUBLE-BUFFERED global_load_lds K/V staging (next-chunk DMA issued after
// the post-S barrier; P reuses the dead K buffer) -> output projection GEMM
// with BM=64 tiles (2 blocks/CU so barrier drains overlap across blocks).
// Workspace layout (bytes):
//   [0,8M)    xb   bf16 [4096,1024]
//   [8M,14M)  wqkv bf16 3x[1024,1024]
//   [14M,16M) wpb  bf16 [1024,1024]
//   [16M,40M) qkv  bf16 q,k:[B,H,T,64], v:[B,H,64,T]
//   [40M,48M) yb   bf16 [4096,1024]
// ---------------------------------------------------------------------------

typedef __attribute__((ext_vector_type(8))) short bf16x8;
typedef __attribute__((ext_vector_type(8))) unsigned short u16x8;
typedef __attribute__((ext_vector_type(4))) float f32x4;

__device__ __forceinline__ float bf2f(unsigned short u) {
  union { unsigned u; float f; } x; x.u = ((unsigned)u) << 16; return x.f;
}
__device__ __forceinline__ unsigned short f2bf(float f) {
  union { float f; unsigned u; } x; x.f = f;
  unsigned r = x.u + 0x7FFFu + ((x.u >> 16) & 1u);  // RNE
  return (unsigned short)(r >> 16);
}

#define GLOAD_LDS16(g, l)                                                     \
  __builtin_amdgcn_global_load_lds(                                           \
      (__attribute__((address_space(1))) void*)(g),                           \
      (__attribute__((address_space(3))) void*)(l), 16, 0, 0)

// ---------------- fp32 -> bf16 (RNE), all 5 tensors in one launch ----------
__global__ void cvt_all(const float* __restrict__ x, const float* __restrict__ Wq,
                        const float* __restrict__ Wk, const float* __restrict__ Wv,
                        const float* __restrict__ Wp, unsigned short* __restrict__ xb,
                        unsigned short* __restrict__ wqkv,
                        unsigned short* __restrict__ wpb) {
  int i = blockIdx.x * 256 + threadIdx.x;  // grid covers exactly 2097152
  const float* src;
  unsigned short* dst;
  int off;
  if (i < 1048576)      { src = x;  dst = xb;             off = i; }
  else if (i < 1310720) { src = Wq; dst = wqkv;           off = i - 1048576; }
  else if (i < 1572864) { src = Wk; dst = wqkv + 1048576; off = i - 1310720; }
  else if (i < 1835008) { src = Wv; dst = wqkv + 2097152; off = i - 1572864; }
  else                  { src = Wp; dst = wpb;            off = i - 1835008; }
  float4 v = ((const float4*)src)[off];
  ushort4 o;
  o.x = f2bf(v.x); o.y = f2bf(v.y); o.z = f2bf(v.z); o.w = f2bf(v.w);
  ((ushort4*)dst)[off] = o;
}

// ---------------- fused QKV bf16 GEMM (m97 structure, known-good 44us) -----
// C[m][n] = sum_k A[m][k]*W[n][k] + bias[n]; 128x128 tile, BK=32, 4 waves.
// bf16 scatter; proj 0/1 (q/k) -> [b,h,t,d]; proj 2 (v) -> [b,h,d,t].
__global__ __launch_bounds__(256) void gemm_qkv(
    const unsigned short* __restrict__ A, const unsigned short* __restrict__ Wall,
    const float* __restrict__ b0, const float* __restrict__ b1,
    const float* __restrict__ b2, unsigned short* __restrict__ outp) {
  constexpr int K = 1024;
  __shared__ __align__(16) unsigned short As[128 * 32];
  __shared__ __align__(16) unsigned short Bs[128 * 32];
  int tid = threadIdx.x;
  int m0 = blockIdx.x * 128;
  int proj = blockIdx.y >> 3;
  int n0 = (blockIdx.y & 7) * 128;
  const unsigned short* W = Wall + (size_t)proj * (K * 1024);
  const float* bias = (proj == 0) ? b0 : ((proj == 1) ? b1 : b2);
  unsigned short* out = outp + (size_t)proj * 4194304;
  int w = tid >> 6, lane = tid & 63;
  int wm = (w >> 1) * 64, wn = (w & 1) * 64;
  int lm = lane & 15, quad = lane >> 4;

  f32x4 acc[4][4];
#pragma unroll
  for (int mi = 0; mi < 4; ++mi)
#pragma unroll
    for (int ni = 0; ni < 4; ++ni) acc[mi][ni] = (f32x4){0.f, 0.f, 0.f, 0.f};

  int o0 = tid * 16, o1 = o0 + 4096;
  int r0 = o0 >> 6, cb0 = o0 & 63;
  int r1 = o1 >> 6, cb1 = o1 & 63;
  const char* a0 = (const char*)A + (size_t)(m0 + r0) * (K * 2) + cb0;
  const char* a1 = (const char*)A + (size_t)(m0 + r1) * (K * 2) + cb1;
  const char* w0 = (const char*)W + (size_t)(n0 + r0) * (K * 2) + cb0;
  const char* w1 = (const char*)W + (size_t)(n0 + r1) * (K * 2) + cb1;
  char* lA = (char*)As;
  char* lB = (char*)Bs;

  for (int k0 = 0; k0 < K; k0 += 32) {
    GLOAD_LDS16(a0 + k0 * 2, lA + o0);
    GLOAD_LDS16(a1 + k0 * 2, lA + o1);
    GLOAD_LDS16(w0 + k0 * 2, lB + o0);
    GLOAD_LDS16(w1 + k0 * 2, lB + o1);
    __syncthreads();
    bf16x8 af[4], bfv[4];
#pragma unroll
    for (int mi = 0; mi < 4; ++mi)
      af[mi] = *(const bf16x8*)(As + (wm + mi * 16 + lm) * 32 + quad * 8);
#pragma unroll
    for (int ni = 0; ni < 4; ++ni)
      bfv[ni] = *(const bf16x8*)(Bs + (wn + ni * 16 + lm) * 32 + quad * 8);
#pragma unroll
    for (int mi = 0; mi < 4; ++mi)
#pragma unroll
      for (int ni = 0; ni < 4; ++ni)
        acc[mi][ni] = __builtin_amdgcn_mfma_f32_16x16x32_bf16(
            af[mi], bfv[ni], acc[mi][ni], 0, 0, 0);
    __syncthreads();
  }
  // epilogue: C/D layout col=lane&15, row=quad*4+reg
#pragma unroll
  for (int mi = 0; mi < 4; ++mi) {
#pragma unroll
    for (int ni = 0; ni < 4; ++ni) {
      int gn = n0 + wn + ni * 16 + lm;
      float bv = bias[gn];
#pragma unroll
      for (int r = 0; r < 4; ++r) {
        int gm = m0 + wm + mi * 16 + quad * 4 + r;
        float val = acc[mi][ni][r] + bv;
        int bb = gm >> 11, tt = gm & 2047;
        int hh = gn >> 6, dd = gn & 63;
        size_t idx;
        if (proj == 2)  // V transposed: [b,h,d,t]
          idx = (((size_t)bb * 16 + hh) * 64 + dd) * 2048 + tt;
        else            // Q,K: [b,h,t,d]
          idx = (((size_t)bb * 16 + hh) * 2048 + tt) * 64 + dd;
        out[idx] = f2bf(val);
      }
    }
  }
}

// ---------------- output projection GEMM, BM=64 (2 blocks/CU) --------------
// C fp32 [4096,1024]; 64x128 tile, 4 waves each 32x64, BK=32.
// grid 64x8 = 512 blocks = 2/CU: one block's vmcnt drain overlaps the
// other's MFMA (round-5: 256 blocks = 1/CU left every drain exposed).
__global__ __launch_bounds__(256) void gemm_p64(
    const unsigned short* __restrict__ A, const unsigned short* __restrict__ W,
    const float* __restrict__ bias, float* __restrict__ out) {
  constexpr int K = 1024;
  __shared__ __align__(16) unsigned short As[64 * 32];   // 4 KB
  __shared__ __align__(16) unsigned short Bs[128 * 32];  // 8 KB
  int tid = threadIdx.x;
  int m0 = blockIdx.x * 64, n0 = blockIdx.y * 128;
  int w = tid >> 6, lane = tid & 63;
  int wm = (w >> 1) * 32, wn = (w & 1) * 64;
  int lm = lane & 15, quad = lane >> 4;

  f32x4 acc[2][4];
#pragma unroll
  for (int mi = 0; mi < 2; ++mi)
#pragma unroll
    for (int ni = 0; ni < 4; ++ni) acc[mi][ni] = (f32x4){0.f, 0.f, 0.f, 0.f};

  int o0 = tid * 16, o1 = o0 + 4096;
  int r0 = o0 >> 6, cb0 = o0 & 63;
  int r1 = o1 >> 6, cb1 = o1 & 63;
  const char* ag = (const char*)A + (size_t)(m0 + r0) * (K * 2) + cb0;
  const char* w0 = (const char*)W + (size_t)(n0 + r0) * (K * 2) + cb0;
  const char* w1 = (const char*)W + (size_t)(n0 + r1) * (K * 2) + cb1;
  char* lA = (char*)As;
  char* lB = (char*)Bs;

  for (int k0 = 0; k0 < K; k0 += 32) {
    GLOAD_LDS16(ag + k0 * 2, lA + o0);  // 4 KB A-tile: one instr, all threads
    GLOAD_LDS16(w0 + k0 * 2, lB + o0);
    GLOAD_LDS16(w1 + k0 * 2, lB + o1);
    __syncthreads();
    bf16x8 af[2], bfv[4];
#pragma unroll
    for (int mi = 0; mi < 2; ++mi)
      af[mi] = *(const bf16x8*)(As + (wm + mi * 16 + lm) * 32 + quad * 8);
#pragma unroll
    for (int ni = 0; ni < 4; ++ni)
      bfv[ni] = *(const bf16x8*)(Bs + (wn + ni * 16 + lm) * 32 + quad * 8);
#pragma unroll
    for (int mi = 0; mi < 2; ++mi)
#pragma unroll
      for (int ni = 0; ni < 4; ++ni)
        acc[mi][ni] = __builtin_amdgcn_mfma_f32_16x16x32_bf16(
            af[mi], bfv[ni], acc[mi][ni], 0, 0, 0);
    __syncthreads();
  }
#pragma unroll
  for (int mi = 0; mi < 2; ++mi) {
#pragma unroll
    for (int ni = 0; ni < 4; ++ni) {
      int gn = n0 + wn + ni * 16 + lm;
      float bv = bias[gn];
#pragma unroll
      for (int r = 0; r < 4; ++r) {
        int gm = m0 + wm + mi * 16 + quad * 4 + r;
        out[(size_t)gm * 1024 + gn] = acc[mi][ni][r] + bv;
      }
    }
  }
}

// ---------------- banded MFMA flash attention, double-buffered DMA ---------
// 1 block = 64 queries, 4 waves x 16 queries. K/V chunks staged via
// global_load_lds into stride-144B rows (slot gather: s -> row s/9, col s%9,
// col 8 = pad redirected to row base) -> conflict-free ds_read_b128 frags.
// Loop: barrier1 (chunk resident) -> S=QK^T -> barrier2 (K reads done) ->
// issue NEXT chunk DMA into other buffer (overlaps softmax+PV; drained by
// next barrier1) -> P into dead K buffer -> PV. Ps eliminated: 4 buffers
// = 36.9 KB -> 4 blocks/CU.
__global__ __launch_bounds__(256) void attn_band_mfma(
    const unsigned short* __restrict__ qb, const unsigned short* __restrict__ kb,
    const unsigned short* __restrict__ vtg, unsigned short* __restrict__ yb) {
  __shared__ __align__(16) unsigned short Kb[2][64 * 72];
  __shared__ __align__(16) unsigned short Vb[2][64 * 72];
  int bid = blockIdx.x;
  int qt = bid & 31, h = (bid >> 5) & 15, b = bid >> 9;
  int q0b = qt * 64;
  int tid = threadIdx.x;
  int lane = tid & 63;
  int w = tid >> 6;
  int m = lane & 15, quad = lane >> 4;
  int wq = w * 16;
  int tq0 = q0b + wq;
  size_t hb = ((size_t)(b * 16 + h)) * (2048 * 64);
  size_t vhb = ((size_t)(b * 16 + h)) * (64 * 2048);
  const char* kgb = (const char*)(kb + hb);    // K rows: 128 B stride
  const char* vgb = (const char*)(vtg + vhb);  // Vt rows: 4096 B stride

  // DMA slots: 0..575 = 64 rows x 9 x 16B; slot%9==8 is pad (addr->row base).
  int sA = tid, sB = tid + 256, sC = 512 + (tid & 63);
  int rA = sA / 9, kA = sA - rA * 9;
  int rB = sB / 9, kB = sB - rB * 9;
  int rC = sC / 9, kC = sC - rC * 9;
  int okA = (kA < 8) ? kA : 0, okB = (kB < 8) ? kB : 0, okC = (kC < 8) ? kC : 0;
  int offKA = rA * 128 + okA * 16, offVA = rA * 4096 + okA * 16;
  int offKB = rB * 128 + okB * 16, offVB = rB * 4096 + okB * 16;
  int offKC = rC * 128 + okC * 16, offVC = rC * 4096 + okC * 16;

  int jlo = q0b - 256;
  if (jlo < 0) jlo = 0;

  // prologue DMA: chunk jlo -> buffers[0] (flies during Q-frag loads)
  {
    const char* kg = kgb + (size_t)jlo * 128;
    const char* vg = vgb + (size_t)jlo * 2;
    char* kd = (char*)Kb[0];
    char* vd = (char*)Vb[0];
    GLOAD_LDS16(kg + offKA, kd + sA * 16);
    GLOAD_LDS16(kg + offKB, kd + sB * 16);
    GLOAD_LDS16(vg + offVA, vd + sA * 16);
    GLOAD_LDS16(vg + offVB, vd + sB * 16);
    if (tid < 128) {
      const char* g = (tid < 64) ? (kg + offKC) : (vg + offVC);
      char* l = ((tid < 64) ? kd : vd) + sC * 16;
      GLOAD_LDS16(g, l);
    }
  }

  // Q A-frags (held all kernel)
  const unsigned short* qrow = qb + hb + (size_t)(tq0 + m) * 64;
  bf16x8 af0 = *(const bf16x8*)(qrow + quad * 8);
  bf16x8 af1 = *(const bf16x8*)(qrow + 32 + quad * 8);

  f32x4 oacc[4];
#pragma unroll
  for (int di = 0; di < 4; ++di) oacc[di] = (f32x4){0.f, 0.f, 0.f, 0.f};
  float lpart[4] = {0.f, 0.f, 0.f, 0.f};

  int cur = 0;
  for (int c0 = jlo; c0 <= q0b; c0 += 64, cur ^= 1) {
    __syncthreads();  // chunk c0 resident (drains its DMA)
    const unsigned short* Kc = Kb[cur];
    const unsigned short* Vc = Vb[cur];
    // ---- S = Q K^T --------------------------------------------------------
    f32x4 sacc[4];
#pragma unroll
    for (int ni = 0; ni < 4; ++ni) sacc[ni] = (f32x4){0.f, 0.f, 0.f, 0.f};
#pragma unroll
    for (int ni = 0; ni < 4; ++ni) {
      bf16x8 k0 = *(const bf16x8*)(Kc + (ni * 16 + m) * 72 + quad * 8);
      bf16x8 k1 = *(const bf16x8*)(Kc + (ni * 16 + m) * 72 + 32 + quad * 8);
      sacc[ni] = __builtin_amdgcn_mfma_f32_16x16x32_bf16(af0, k0, sacc[ni], 0, 0, 0);
      sacc[ni] = __builtin_amdgcn_mfma_f32_16x16x32_bf16(af1, k1, sacc[ni], 0, 0, 0);
    }
    __syncthreads();  // all waves done reading Kc -> safe to reuse for P
    // ---- issue next-chunk DMA (overlaps softmax + PV) ---------------------
    if (c0 < q0b) {
      const char* kg = kgb + (size_t)(c0 + 64) * 128;
      const char* vg = vgb + (size_t)(c0 + 64) * 2;
      char* kd = (char*)Kb[cur ^ 1];
      char* vd = (char*)Vb[cur ^ 1];
      GLOAD_LDS16(kg + offKA, kd + sA * 16);
      GLOAD_LDS16(kg + offKB, kd + sB * 16);
      GLOAD_LDS16(vg + offVA, vd + sA * 16);
      GLOAD_LDS16(vg + offVB, vd + sB * 16);
      if (tid < 128) {
        const char* g = (tid < 64) ? (kg + offKC) : (vg + offVC);
        char* l = ((tid < 64) ? kd : vd) + sC * 16;
        GLOAD_LDS16(g, l);
      }
    }
    // ---- softmax piece: mask, exp, row sums, P -> dead K buffer -----------
    unsigned short* Pw = (unsigned short*)Kc;
#pragma unroll
    for (int ni = 0; ni < 4; ++ni) {
      int j = c0 + ni * 16 + m;
#pragma unroll
      for (int r = 0; r < 4; ++r) {
        int t = tq0 + quad * 4 + r;
        float e = __expf(sacc[ni][r] * 0.125f);
        e = ((unsigned)(t - j) <= 256u) ? e : 0.f;  // causal + band
        lpart[r] += e;
        Pw[(wq + quad * 4 + r) * 72 + ni * 16 + m] = f2bf(e);
      }
    }
    // ---- O += P V (P A-frags: own wave rows only -> no barrier needed) ----
#pragma unroll
    for (int ks = 0; ks < 2; ++ks) {
      bf16x8 a = *(const bf16x8*)(Pw + (wq + m) * 72 + ks * 32 + quad * 8);
#pragma unroll
      for (int di = 0; di < 4; ++di) {
        bf16x8 vfr = *(const bf16x8*)(Vc + (di * 16 + m) * 72 + ks * 32 + quad * 8);
        oacc[di] = __builtin_amdgcn_mfma_f32_16x16x32_bf16(a, vfr, oacc[di], 0, 0, 0);
      }
    }
  }
  // ---- finalize -----------------------------------------------------------
#pragma unroll
  for (int mask = 1; mask <= 8; mask <<= 1)
#pragma unroll
    for (int r = 0; r < 4; ++r) lpart[r] += __shfl_xor(lpart[r], mask, 64);
  float inv[4];
#pragma unroll
  for (int r = 0; r < 4; ++r) inv[r] = 1.f / lpart[r];
  // scatter normalized O into own rows of Kb[0] (wave-private), then store
  unsigned short* R = &Kb[0][0];
#pragma unroll
  for (int di = 0; di < 4; ++di)
#pragma unroll
    for (int r = 0; r < 4; ++r)
      R[(wq + quad * 4 + r) * 72 + di * 16 + m] = f2bf(oacc[di][r] * inv[r]);
  size_t orow = (size_t)b * 2048 + tq0;
#pragma unroll
  for (int v2 = 0; v2 < 2; ++v2) {
    int v = v2 * 64 + lane;
    int q = v >> 3, dg = v & 7;
    u16x8 val = *(const u16x8*)(R + (wq + q) * 72 + dg * 8);
    *(u16x8*)(yb + (orow + q) * 1024 + h * 64 + dg * 8) = val;
  }
}

// ---------------------------------------------------------------------------
extern "C" void kernel_launch(void* const* d_in, const int* in_sizes, int n_in,
                              void* d_out, int out_size, void* d_ws,
                              size_t ws_size, hipStream_t stream) {
  const float* x  = (const float*)d_in[0];
  const float* Wq = (const float*)d_in[1];
  const float* bq = (const float*)d_in[2];
  const float* Wk = (const float*)d_in[3];
  const float* bk = (const float*)d_in[4];
  const float* Wv = (const float*)d_in[5];
  const float* bv = (const float*)d_in[6];
  const float* Wp = (const float*)d_in[7];
  const float* bp = (const float*)d_in[8];
  float* out = (float*)d_out;

  char* ws = (char*)d_ws;
  unsigned short* xb   = (unsigned short*)(ws);
  unsigned short* wqkv = (unsigned short*)(ws + (8ull << 20));
  unsigned short* wpb  = (unsigned short*)(ws + (14ull << 20));
  unsigned short* qkv  = (unsigned short*)(ws + (16ull << 20));
  unsigned short* yb   = (unsigned short*)(ws + (40ull << 20));

  cvt_all<<<8192, 256, 0, stream>>>(x, Wq, Wk, Wv, Wp, xb, wqkv, wpb);
  gemm_qkv<<<dim3(32, 24), 256, 0, stream>>>(xb, wqkv, bq, bk, bv, qkv);
  attn_band_mfma<<<1024, 256, 0, stream>>>(qkv, qkv + 4194304ull,
                                           qkv + 8388608ull, yb);
  gemm_p64<<<dim3(64, 8), 256, 0, stream>>>(yb, wpb, bp, out);
}